// Round 1
// baseline (61.758 us; speedup 1.0000x reference)
//
#include <hip/hip_runtime.h>
#include <math.h>

#define S_LEN 512
#define D_DIM 48
#define N_DIM 96
#define L_NUM 2
#define V_NUM 113
#define B_NUM 2048

#define BB 4                       // batches per block, kernel 1
#define K1_THREADS (BB * D_DIM)    // 192
#define GB 8                       // batches per block, kernel 2
#define K2_THREADS 256

// f32 constants matching numpy/jax float32 exactly
__device__ constexpr float PHIF    = (float)1.6180339887498949;   // np.float32(PHI)
__device__ constexpr float TWOPIF  = (float)6.283185307179586;    // np.float32(2*pi)
__device__ constexpr float SCALEF  = 4096.0f / TWOPIF;            // f32 IEEE divide (constexpr)
__device__ constexpr float SQRT2F  = (float)1.4142135623730951;
__device__ constexpr float INV4096 = 1.0f / 4096.0f;

// Kernel 1: the 512-step quantized-phase recurrence.
// State per (b,d) chain: sv = sin(2*pi*(idx/4096 + 1/8)), so that
// s = sin_tab[idx] + cos_tab[idx] == sqrt(2)*sv (up to ~1ulp; contractive map).
__global__ __launch_bounds__(K1_THREADS) void rin_scan_kernel(
    const int*   __restrict__ ids,   // [B,S]
    const float* __restrict__ emb,   // [V, 2D]
    float*       __restrict__ hout)  // stash h into d_out[b*113 + d], d<48
{
    __shared__ float2 coef[V_NUM * D_DIM];  // {sqrt2/(1+|w|), b}
    __shared__ int    toks[BB][S_LEN];

    const int tid = threadIdx.x;
    const int b0  = blockIdx.x * BB;

    // build per-(token,d) coefficient table (same for all blocks; cheap)
    for (int i = tid; i < V_NUM * D_DIM; i += K1_THREADS) {
        int v = i / D_DIM, d = i - v * D_DIM;
        float w = emb[v * (2 * D_DIM) + d];
        float b = emb[v * (2 * D_DIM) + D_DIM + d];
        float wl = 1.0f + fabsf(w);
        coef[i] = make_float2(SQRT2F / wl, b);
    }
    // preload this block's token streams (contiguous rows of ids)
    const int* idsrc = ids + (size_t)b0 * S_LEN;
    for (int i = tid; i < BB * S_LEN; i += K1_THREADS) {
        ((int*)toks)[i] = idsrc[i];
    }
    __syncthreads();

    const int bl = tid / D_DIM;
    const int d  = tid - bl * D_DIM;
    const int* mytok = toks[bl];

    float sv = 0.0f;   // s = sqrt2*sv; initial h_real=h_imag=0 -> s=0 -> sv=0
    float tf = 0.0f;
#pragma unroll 4
    for (int t = 0; t < S_LEN; ++t) {
        int tok = mytok[t];
        float2 cf = coef[tok * D_DIM + d];
        float q = sv * cf.x;                 // (h_real+h_imag)/wavelength
        float tphi = tf * PHIF;              // t_val, rounded separately
        asm("" : "+v"(tphi));                // block fma-contraction into the add
        float theta = (q + cf.y) + tphi;     // same assoc order as reference
        float u = theta * SCALEF;
        float fr = __builtin_amdgcn_fractf(rintf(u) * INV4096); // (idx mod 4096)/4096
        sv = __builtin_amdgcn_sinf(fr + 0.125f);                // sin(theta_q + pi/4)/sqrt2... (rev)
        tf += 1.0f;
    }
    hout[(size_t)(b0 + bl) * V_NUM + d] = SQRT2F * sv;   // h = h_real + h_imag at final step
}

// Kernel 2: final-step MLP (2 layers) + output projection, 8 b's per block.
__global__ __launch_bounds__(K2_THREADS) void rin_head_kernel(
    const float* __restrict__ layer_W,     // [L,N,D]
    const float* __restrict__ layer_bias,  // [L,N]
    const float* __restrict__ proj_real,   // [L,D,N]
    const float* __restrict__ proj_imag,   // [L,D,N]
    const float* __restrict__ out_proj,    // [V,D]
    float*       __restrict__ out)         // [B,V]; h stashed at [b][0..48)
{
    __shared__ float h[GB][D_DIM];
    __shared__ float cs[GB][N_DIM];
    __shared__ float sn[GB][N_DIM];

    const int tid = threadIdx.x;
    const int b0  = blockIdx.x * GB;

    for (int i = tid; i < GB * D_DIM; i += K2_THREADS) {
        int g = i / D_DIM, d = i - g * D_DIM;
        h[g][d] = out[(size_t)(b0 + g) * V_NUM + d];
    }
    __syncthreads();

    const float tphi = 511.0f * PHIF;

    for (int l = 0; l < L_NUM; ++l) {
        // th = h @ W^T + bias + t_val ; quantized sin/cos
        for (int i = tid; i < GB * N_DIM; i += K2_THREADS) {
            int g = i / N_DIM, n = i - g * N_DIM;
            const float* Wr = layer_W + (size_t)(l * N_DIM + n) * D_DIM;
            float acc = 0.0f;
#pragma unroll
            for (int d = 0; d < D_DIM; ++d) acc += h[g][d] * Wr[d];
            float th = (acc + layer_bias[l * N_DIM + n]) + tphi;
            float u = th * SCALEF;
            float fr = __builtin_amdgcn_fractf(rintf(u) * INV4096);
            cs[g][n] = __builtin_amdgcn_cosf(fr);
            sn[g][n] = __builtin_amdgcn_sinf(fr);
        }
        __syncthreads();
        // out = c @ proj_real^T + s @ proj_imag^T ; h += silu(out)
        for (int i = tid; i < GB * D_DIM; i += K2_THREADS) {
            int g = i / D_DIM, d = i - g * D_DIM;
            const float* pr = proj_real + (size_t)(l * D_DIM + d) * N_DIM;
            const float* pi = proj_imag + (size_t)(l * D_DIM + d) * N_DIM;
            float acc = 0.0f;
#pragma unroll
            for (int n = 0; n < N_DIM; ++n) acc += cs[g][n] * pr[n] + sn[g][n] * pi[n];
            float sig = 1.0f / (1.0f + expf(-acc));
            h[g][d] += acc * sig;
        }
        __syncthreads();
    }

    // out = h @ output_proj^T
    for (int i = tid; i < GB * V_NUM; i += K2_THREADS) {
        int g = i / V_NUM, v = i - g * V_NUM;
        const float* opr = out_proj + (size_t)v * D_DIM;
        float acc = 0.0f;
#pragma unroll
        for (int d = 0; d < D_DIM; ++d) acc += h[g][d] * opr[d];
        out[(size_t)(b0 + g) * V_NUM + v] = acc;
    }
}

extern "C" void kernel_launch(void* const* d_in, const int* in_sizes, int n_in,
                              void* d_out, int out_size, void* d_ws, size_t ws_size,
                              hipStream_t stream) {
    const int*   ids  = (const int*)d_in[0];
    const float* emb  = (const float*)d_in[1];
    const float* W    = (const float*)d_in[2];
    const float* bias = (const float*)d_in[3];
    const float* pr   = (const float*)d_in[4];
    const float* pi   = (const float*)d_in[5];
    const float* op   = (const float*)d_in[6];
    float* out = (float*)d_out;

    hipLaunchKernelGGL(rin_scan_kernel, dim3(B_NUM / BB), dim3(K1_THREADS), 0, stream,
                       ids, emb, out);
    hipLaunchKernelGGL(rin_head_kernel, dim3(B_NUM / GB), dim3(K2_THREADS), 0, stream,
                       W, bias, pr, pi, op, out);
}

// Round 2
// 49.845 us; speedup vs baseline: 1.2390x; 1.2390x over previous
//
#include <hip/hip_runtime.h>
#include <math.h>

#define S_LEN 512
#define D_DIM 48
#define N_DIM 96
#define L_NUM 2
#define V_NUM 113
#define B_NUM 2048

#define BB 4                       // batches per block
#define K1_THREADS (BB * D_DIM)    // 192 threads, 3 waves
#define CH 8                       // scan chunk (software pipeline unit)
#define NCH (S_LEN / CH)           // 64 chunks

// f32 constants matching numpy/jax float32 exactly
__device__ constexpr float PHIF    = (float)1.6180339887498949;   // np.float32(PHI)
__device__ constexpr float TWOPIF  = (float)6.283185307179586;    // np.float32(2*pi)
__device__ constexpr float SCALEF  = 4096.0f / TWOPIF;            // f32 IEEE divide (constexpr)
__device__ constexpr float SQRT2F  = (float)1.4142135623730951;
__device__ constexpr float INV4096 = 1.0f / 4096.0f;

__global__ __launch_bounds__(K1_THREADS) void rin_fused_kernel(
    const int*   __restrict__ ids,         // [B,S]
    const float* __restrict__ emb,         // [V,2D]
    const float* __restrict__ layer_W,     // [L,N,D]
    const float* __restrict__ layer_bias,  // [L,N]
    const float* __restrict__ proj_real,   // [L,D,N]
    const float* __restrict__ proj_imag,   // [L,D,N]
    const float* __restrict__ out_proj,    // [V,D]
    float*       __restrict__ out)         // [B,V]
{
    __shared__ float2 coef[V_NUM * D_DIM];            // {sqrt2/(1+|w|), b}
    __shared__ int    toks[BB][S_LEN];                // token byte-offsets (tok*384)
    __shared__ __align__(16) float hsm[BB][D_DIM];
    __shared__ __align__(16) float csm[BB][N_DIM];
    __shared__ __align__(16) float ssm[BB][N_DIM];

    const int tid = threadIdx.x;
    const int b0  = blockIdx.x * BB;

    // per-(token,d) coefficient table
    for (int i = tid; i < V_NUM * D_DIM; i += K1_THREADS) {
        int v = i / D_DIM, d = i - v * D_DIM;
        float w = emb[v * (2 * D_DIM) + d];
        float b = emb[v * (2 * D_DIM) + D_DIM + d];
        coef[i] = make_float2(SQRT2F / (1.0f + fabsf(w)), b);
    }
    // token streams, pre-scaled to coef-row byte offsets
    const int* idsrc = ids + (size_t)b0 * S_LEN;
    for (int i = tid; i < BB * S_LEN; i += K1_THREADS)
        ((int*)toks)[i] = idsrc[i] * (D_DIM * 8);
    __syncthreads();

    const int bl = tid / D_DIM;
    const int d  = tid - bl * D_DIM;
    const int* mytok = toks[bl];
    const char* myCoef = (const char*)coef + d * 8;

    // -------- software-pipelined scan: depth-2 register prefetch --------
    int    tokN[CH], tokT[CH];
    float2 cfA[CH], cfB[CH];

#pragma unroll
    for (int i = 0; i < CH; ++i) tokT[i] = mytok[i];                  // chunk 0 toks
#pragma unroll
    for (int i = 0; i < CH; ++i) cfA[i] = *(const float2*)(myCoef + tokT[i]);
#pragma unroll
    for (int i = 0; i < CH; ++i) tokN[i] = mytok[CH + i];             // chunk 1 toks

    float sv = 0.0f;   // s = sqrt2*sv
    float tf = 0.0f;

    for (int c = 0; c < NCH; ++c) {
        // issue coef loads for chunk c+1 (tokN resident -> addresses ready now)
#pragma unroll
        for (int i = 0; i < CH; ++i) cfB[i] = *(const float2*)(myCoef + tokN[i]);
        // issue token loads for chunk c+2 (clamped in-bounds; unused at the tail)
        int base = (c + 2 < NCH) ? (c + 2) * CH : 0;
#pragma unroll
        for (int i = 0; i < CH; ++i) tokT[i] = mytok[base + i];
        // compute chunk c — pure-VALU chain, bit-identical to validated round-1 math
#pragma unroll
        for (int i = 0; i < CH; ++i) {
            float2 cf = cfA[i];
            float q = sv * cf.x;                 // (h_real+h_imag)/wavelength
            float tphi = tf * PHIF;              // t_val, rounded separately
            asm("" : "+v"(tphi));                // block fma-contraction into the add
            float theta = (q + cf.y) + tphi;     // same assoc order as reference
            float u = theta * SCALEF;
            float fr = __builtin_amdgcn_fractf(rintf(u) * INV4096);
            sv = __builtin_amdgcn_sinf(fr + 0.125f);   // sin(theta_q + pi/4)/sqrt2 (rev)
            tf += 1.0f;
        }
        // rotate pipeline registers
#pragma unroll
        for (int i = 0; i < CH; ++i) { cfA[i] = cfB[i]; tokN[i] = tokT[i]; }
    }

    hsm[bl][d] = SQRT2F * sv;                    // h = h_real + h_imag at t=511
    __syncthreads();

    // -------- fused head: 2-layer MLP + output projection for BB batches --------
    const float tphi511 = 511.0f * PHIF;

#pragma unroll
    for (int l = 0; l < L_NUM; ++l) {
        // th = h @ W^T + bias + t_val ; quantized sin/cos  (BB*N = 384 tasks, 2/thread)
#pragma unroll
        for (int r = 0; r < (BB * N_DIM) / K1_THREADS; ++r) {
            int i = tid + r * K1_THREADS;
            int g = i / N_DIM, n = i - g * N_DIM;
            const float4* Wr = (const float4*)(layer_W + ((size_t)l * N_DIM + n) * D_DIM);
            const float* hg = hsm[g];
            float acc = 0.0f;
#pragma unroll
            for (int k = 0; k < D_DIM / 4; ++k) {
                float4 w4 = Wr[k];
                acc += hg[4*k+0] * w4.x; acc += hg[4*k+1] * w4.y;
                acc += hg[4*k+2] * w4.z; acc += hg[4*k+3] * w4.w;
            }
            float th = (acc + layer_bias[l * N_DIM + n]) + tphi511;
            float u = th * SCALEF;
            float fr = __builtin_amdgcn_fractf(rintf(u) * INV4096);
            csm[g][n] = __builtin_amdgcn_cosf(fr);
            ssm[g][n] = __builtin_amdgcn_sinf(fr);
        }
        __syncthreads();
        // out = c @ pr^T + s @ pi^T ; h += silu(out)   (BB*D = 192 tasks, 1/thread)
        {
            const float4* pr = (const float4*)(proj_real + ((size_t)l * D_DIM + d) * N_DIM);
            const float4* pi = (const float4*)(proj_imag + ((size_t)l * D_DIM + d) * N_DIM);
            const float4* c4p = (const float4*)csm[bl];
            const float4* s4p = (const float4*)ssm[bl];
            float acc = 0.0f;
#pragma unroll
            for (int k = 0; k < N_DIM / 4; ++k) {
                float4 c4 = c4p[k], s4 = s4p[k];
                float4 p4 = pr[k],  q4 = pi[k];
                acc += c4.x * p4.x + s4.x * q4.x;
                acc += c4.y * p4.y + s4.y * q4.y;
                acc += c4.z * p4.z + s4.z * q4.z;
                acc += c4.w * p4.w + s4.w * q4.w;
            }
            float sig = 1.0f / (1.0f + __expf(-acc));
            hsm[bl][d] += acc * sig;
        }
        __syncthreads();
    }

    // out = h @ output_proj^T   (BB*V = 452 tasks)
    for (int i = tid; i < BB * V_NUM; i += K1_THREADS) {
        int g = i / V_NUM, v = i - g * V_NUM;
        const float4* opr = (const float4*)(out_proj + (size_t)v * D_DIM);
        const float* hg = hsm[g];
        float acc = 0.0f;
#pragma unroll
        for (int k = 0; k < D_DIM / 4; ++k) {
            float4 o4 = opr[k];
            acc += hg[4*k+0] * o4.x; acc += hg[4*k+1] * o4.y;
            acc += hg[4*k+2] * o4.z; acc += hg[4*k+3] * o4.w;
        }
        out[(size_t)(b0 + g) * V_NUM + v] = acc;
    }
}

extern "C" void kernel_launch(void* const* d_in, const int* in_sizes, int n_in,
                              void* d_out, int out_size, void* d_ws, size_t ws_size,
                              hipStream_t stream) {
    const int*   ids  = (const int*)d_in[0];
    const float* emb  = (const float*)d_in[1];
    const float* W    = (const float*)d_in[2];
    const float* bias = (const float*)d_in[3];
    const float* pr   = (const float*)d_in[4];
    const float* pi   = (const float*)d_in[5];
    const float* op   = (const float*)d_in[6];
    float* out = (float*)d_out;

    hipLaunchKernelGGL(rin_fused_kernel, dim3(B_NUM / BB), dim3(K1_THREADS), 0, stream,
                       ids, emb, W, bias, pr, pi, op, out);
}

// Round 3
// 48.277 us; speedup vs baseline: 1.2792x; 1.0325x over previous
//
#include <hip/hip_runtime.h>
#include <math.h>

#define S_LEN 512
#define D_DIM 48
#define N_DIM 96
#define L_NUM 2
#define V_NUM 113
#define B_NUM 2048

#define BB 4                       // batches per block
#define K1_THREADS (BB * D_DIM)    // 192 threads, 3 waves
#define CH 8                       // scan chunk (software pipeline unit)
#define NCH (S_LEN / CH)           // 64 chunks

// f32 constants matching numpy/jax float32 exactly
__device__ constexpr float PHIF    = (float)1.6180339887498949;   // np.float32(PHI)
__device__ constexpr float TWOPIF  = (float)6.283185307179586;    // np.float32(2*pi)
__device__ constexpr float SCALEF  = 4096.0f / TWOPIF;            // f32 IEEE divide (constexpr)
__device__ constexpr float SQRT2F  = (float)1.4142135623730951;
__device__ constexpr float INV4096 = 1.0f / 4096.0f;

__global__ __launch_bounds__(K1_THREADS) void rin_fused_kernel(
    const int*   __restrict__ ids,         // [B,S]
    const float* __restrict__ emb,         // [V,2D]
    const float* __restrict__ layer_W,     // [L,N,D]
    const float* __restrict__ layer_bias,  // [L,N]
    const float* __restrict__ proj_real,   // [L,D,N]
    const float* __restrict__ proj_imag,   // [L,D,N]
    const float* __restrict__ out_proj,    // [V,D]
    float*       __restrict__ out)         // [B,V]
{
    __shared__ float2 coef[V_NUM * D_DIM];            // {sqrt2/(1+|w|), b}
    __shared__ int    toks[BB][S_LEN];                // token byte-offsets (tok*384)
    __shared__ __align__(16) float hsm[BB][D_DIM];
    __shared__ __align__(16) float csm[BB][N_DIM];
    __shared__ __align__(16) float ssm[BB][N_DIM];

    const int tid = threadIdx.x;
    const int b0  = blockIdx.x * BB;

    // per-(token,d) coefficient table
    for (int i = tid; i < V_NUM * D_DIM; i += K1_THREADS) {
        int v = i / D_DIM, d = i - v * D_DIM;
        float w = emb[v * (2 * D_DIM) + d];
        float b = emb[v * (2 * D_DIM) + D_DIM + d];
        coef[i] = make_float2(SQRT2F / (1.0f + fabsf(w)), b);
    }
    // token streams, pre-scaled to coef-row byte offsets
    const int* idsrc = ids + (size_t)b0 * S_LEN;
    for (int i = tid; i < BB * S_LEN; i += K1_THREADS)
        ((int*)toks)[i] = idsrc[i] * (D_DIM * 8);
    __syncthreads();

    const int bl = tid / D_DIM;
    const int d  = tid - bl * D_DIM;
    const int* mytok = toks[bl];
    const char* myCoef = (const char*)coef + d * 8;

    // -------- software-pipelined scan: depth-2 register prefetch --------
    int    tokN[CH], tokT[CH];
    float2 cfA[CH], cfB[CH];

#pragma unroll
    for (int i = 0; i < CH; ++i) tokT[i] = mytok[i];                  // chunk 0 toks
#pragma unroll
    for (int i = 0; i < CH; ++i) cfA[i] = *(const float2*)(myCoef + tokT[i]);
#pragma unroll
    for (int i = 0; i < CH; ++i) tokN[i] = mytok[CH + i];             // chunk 1 toks

    float sv = 0.0f;   // s = sqrt2*sv
    float tf = 0.0f;

    for (int c = 0; c < NCH; ++c) {
        // issue coef loads for chunk c+1
#pragma unroll
        for (int i = 0; i < CH; ++i) cfB[i] = *(const float2*)(myCoef + tokN[i]);
        // issue token loads for chunk c+2 (clamped in-bounds; unused at the tail)
        int base = (c + 2 < NCH) ? (c + 2) * CH : 0;
#pragma unroll
        for (int i = 0; i < CH; ++i) tokT[i] = mytok[base + i];
        // compute chunk c — 6-dependent-op chain:
        //   fma(sv,cfx,b) -> +tphi -> *SCALE -> rndne -> fma(inv4096,+1/8) -> sin
        // Same rounding order as reference for all large-magnitude terms; the
        // dropped v_fract is exact (integer-revolution shift, HW periodic sin).
#pragma unroll
        for (int i = 0; i < CH; ++i) {
            float2 cf = cfA[i];
            float tphi = tf * PHIF;              // t_val, rounded separately
            asm("" : "+v"(tphi));                // block contraction/strength-reduction
            float w = __builtin_fmaf(sv, cf.x, cf.y);   // (hr+hi)/wl + b  (fma-fused)
            float theta = w + tphi;              // same assoc order as reference
            float u = theta * SCALEF;
            float r = rintf(u);                  // idx (un-modded; integer-valued f32)
            float x = __builtin_fmaf(r, INV4096, 0.125f); // (idx+512)/4096, exact
            sv = __builtin_amdgcn_sinf(x);       // HW periodic reduction, |x|<=132
            tf += 1.0f;
        }
        // rotate pipeline registers
#pragma unroll
        for (int i = 0; i < CH; ++i) { cfA[i] = cfB[i]; tokN[i] = tokT[i]; }
    }

    hsm[bl][d] = SQRT2F * sv;                    // h = h_real + h_imag at t=511
    __syncthreads();

    // -------- fused head: 2-layer MLP + output projection for BB batches --------
    const float tphi511 = 511.0f * PHIF;

#pragma unroll
    for (int l = 0; l < L_NUM; ++l) {
        // th = h @ W^T + bias + t_val ; quantized sin/cos  (BB*N = 384 tasks)
#pragma unroll
        for (int r = 0; r < (BB * N_DIM) / K1_THREADS; ++r) {
            int i = tid + r * K1_THREADS;
            int g = i / N_DIM, n = i - g * N_DIM;
            const float4* Wr = (const float4*)(layer_W + ((size_t)l * N_DIM + n) * D_DIM);
            const float* hg = hsm[g];
            float acc = 0.0f;
#pragma unroll
            for (int k = 0; k < D_DIM / 4; ++k) {
                float4 w4 = Wr[k];
                acc += hg[4*k+0] * w4.x; acc += hg[4*k+1] * w4.y;
                acc += hg[4*k+2] * w4.z; acc += hg[4*k+3] * w4.w;
            }
            float th = (acc + layer_bias[l * N_DIM + n]) + tphi511;
            float u = th * SCALEF;
            float rr = rintf(u);
            float x = __builtin_fmaf(rr, INV4096, 0.0f);
            csm[g][n] = __builtin_amdgcn_cosf(x);
            ssm[g][n] = __builtin_amdgcn_sinf(x);
        }
        __syncthreads();
        // out = c @ pr^T + s @ pi^T ; h += silu(out)   (BB*D = 192 tasks, 1/thread)
        {
            const float4* pr = (const float4*)(proj_real + ((size_t)l * D_DIM + d) * N_DIM);
            const float4* pi = (const float4*)(proj_imag + ((size_t)l * D_DIM + d) * N_DIM);
            const float4* c4p = (const float4*)csm[bl];
            const float4* s4p = (const float4*)ssm[bl];
            float acc = 0.0f;
#pragma unroll
            for (int k = 0; k < N_DIM / 4; ++k) {
                float4 c4 = c4p[k], s4 = s4p[k];
                float4 p4 = pr[k],  q4 = pi[k];
                acc += c4.x * p4.x + s4.x * q4.x;
                acc += c4.y * p4.y + s4.y * q4.y;
                acc += c4.z * p4.z + s4.z * q4.z;
                acc += c4.w * p4.w + s4.w * q4.w;
            }
            float sig = 1.0f / (1.0f + __expf(-acc));
            hsm[bl][d] += acc * sig;
        }
        __syncthreads();
    }

    // out = h @ output_proj^T   (BB*V = 452 tasks)
    for (int i = tid; i < BB * V_NUM; i += K1_THREADS) {
        int g = i / V_NUM, v = i - g * V_NUM;
        const float4* opr = (const float4*)(out_proj + (size_t)v * D_DIM);
        const float* hg = hsm[g];
        float acc = 0.0f;
#pragma unroll
        for (int k = 0; k < D_DIM / 4; ++k) {
            float4 o4 = opr[k];
            acc += hg[4*k+0] * o4.x; acc += hg[4*k+1] * o4.y;
            acc += hg[4*k+2] * o4.z; acc += hg[4*k+3] * o4.w;
        }
        out[(size_t)(b0 + g) * V_NUM + v] = acc;
    }
}

extern "C" void kernel_launch(void* const* d_in, const int* in_sizes, int n_in,
                              void* d_out, int out_size, void* d_ws, size_t ws_size,
                              hipStream_t stream) {
    const int*   ids  = (const int*)d_in[0];
    const float* emb  = (const float*)d_in[1];
    const float* W    = (const float*)d_in[2];
    const float* bias = (const float*)d_in[3];
    const float* pr   = (const float*)d_in[4];
    const float* pi   = (const float*)d_in[5];
    const float* op   = (const float*)d_in[6];
    float* out = (float*)d_out;

    hipLaunchKernelGGL(rin_fused_kernel, dim3(B_NUM / BB), dim3(K1_THREADS), 0, stream,
                       ids, emb, W, bias, pr, pi, op, out);
}